// Round 1
// baseline (620.218 us; speedup 1.0000x reference)
//
#include <hip/hip_runtime.h>
#include <hip/hip_bf16.h>

#define MD 8192
#define KD 4096
#define ND 4096
#define BM 128
#define BN 128
#define BK 64

typedef __bf16 bf16x8 __attribute__((ext_vector_type(8)));
typedef float f32x4 __attribute__((ext_vector_type(4)));

// XOR swizzle within a [row][BK] bf16 tile (row stride 128B).
// Spreads the 16B slots of 8 consecutive rows across all 32 banks.
__device__ __forceinline__ unsigned swz(unsigned row, unsigned kbyte) {
    return row * (BK * 2u) + (kbyte ^ ((row & 7u) << 4));
}

__device__ __forceinline__ float gelu_ss(float v) {
    float t = 0.7978845608f * fmaf(0.044715f * v * v, v, v);
    float r = t * __builtin_amdgcn_rcpf(1.0f + fabsf(t));
    return 0.5f * v * (1.0f + r);
}

__global__ __launch_bounds__(256, 2) void fused_gemm_lse(
    const float* __restrict__ x, const float* __restrict__ W,
    const float* __restrict__ bias, float* __restrict__ rowsum)
{
    __shared__ alignas(16) __bf16 As[BM * BK];
    __shared__ alignas(16) __bf16 Bs[BN * BK];

    // XCD-bijective block swizzle: grid = 64*32 = 2048, divisible by 8.
    unsigned bid  = blockIdx.x;
    unsigned sbid = (bid & 7u) * (2048u / 8u) + (bid >> 3);
    unsigned bm = sbid / (ND / BN);
    unsigned bn = sbid % (ND / BN);

    const unsigned tid  = threadIdx.x;
    const unsigned lane = tid & 63u;
    const unsigned wid  = tid >> 6;
    const unsigned wr   = wid >> 1;      // wave row (0..1)
    const unsigned wc   = wid & 1u;      // wave col (0..1)
    const unsigned lr   = lane & 15u;    // fragment row/col index
    const unsigned kg   = lane >> 4;     // k-group (0..3)

    const float* gA = x + (size_t)bm * BM * KD;
    const float* gB = W + (size_t)bn * BN * KD;

    f32x4 acc[4][4] = {};

    char* AsB = (char*)&As[0];
    char* BsB = (char*)&Bs[0];

    for (int kt = 0; kt < KD / BK; ++kt) {
        // ---- stage A and B tiles: fp32 global -> bf16 LDS (swizzled) ----
        #pragma unroll
        for (int i = 0; i < 4; ++i) {
            unsigned c    = tid + 256u * i;    // chunk 0..1023 (8 bf16 each)
            unsigned row  = c >> 3;            // 0..127
            unsigned col8 = c & 7u;            // 0..7
            size_t goff = (size_t)row * KD + (size_t)kt * BK + (size_t)col8 * 8u;
            float4 a0 = *(const float4*)(gA + goff);
            float4 a1 = *(const float4*)(gA + goff + 4);
            float4 b0 = *(const float4*)(gB + goff);
            float4 b1 = *(const float4*)(gB + goff + 4);
            bf16x8 va, vb;
            va[0]=(__bf16)a0.x; va[1]=(__bf16)a0.y; va[2]=(__bf16)a0.z; va[3]=(__bf16)a0.w;
            va[4]=(__bf16)a1.x; va[5]=(__bf16)a1.y; va[6]=(__bf16)a1.z; va[7]=(__bf16)a1.w;
            vb[0]=(__bf16)b0.x; vb[1]=(__bf16)b0.y; vb[2]=(__bf16)b0.z; vb[3]=(__bf16)b0.w;
            vb[4]=(__bf16)b1.x; vb[5]=(__bf16)b1.y; vb[6]=(__bf16)b1.z; vb[7]=(__bf16)b1.w;
            *(bf16x8*)(AsB + swz(row, col8 * 16u)) = va;
            *(bf16x8*)(BsB + swz(row, col8 * 16u)) = vb;
        }
        __syncthreads();

        // ---- MFMA compute: 2 k-substeps x 4x4 fragments ----
        #pragma unroll
        for (int ks = 0; ks < 2; ++ks) {
            unsigned kbyte = (unsigned)ks * 64u + kg * 16u;
            bf16x8 af[4], bfr[4];
            #pragma unroll
            for (int mi = 0; mi < 4; ++mi)
                af[mi] = *(const bf16x8*)(AsB + swz(wr * 64u + mi * 16u + lr, kbyte));
            #pragma unroll
            for (int ni = 0; ni < 4; ++ni)
                bfr[ni] = *(const bf16x8*)(BsB + swz(wc * 64u + ni * 16u + lr, kbyte));
            #pragma unroll
            for (int mi = 0; mi < 4; ++mi)
                #pragma unroll
                for (int ni = 0; ni < 4; ++ni)
                    acc[mi][ni] = __builtin_amdgcn_mfma_f32_16x16x32_bf16(
                        af[mi], bfr[ni], acc[mi][ni], 0, 0, 0);
        }
        __syncthreads();
    }

    // ---- epilogue: bias + leaky^2 + gelu_ss^2 + exp + per-row partial sums ----
    // C/D layout (16x16x32): col = lane&15, row = (lane>>4)*4 + j
    unsigned row_base = bm * BM + wr * 64u;
    unsigned col_base = bn * BN + wc * 64u;
    #pragma unroll
    for (int mi = 0; mi < 4; ++mi) {
        float s[4] = {0.f, 0.f, 0.f, 0.f};
        #pragma unroll
        for (int ni = 0; ni < 4; ++ni) {
            float bb = bias[col_base + ni * 16u + lr];
            #pragma unroll
            for (int j = 0; j < 4; ++j) {
                float v = acc[mi][ni][j] + bb;
                v = v > 0.0f ? v : 1e-4f * v;       // two leaky-relus fused
                v = gelu_ss(gelu_ss(v));
                s[j] += __expf(v);
            }
        }
        #pragma unroll
        for (int j = 0; j < 4; ++j) {
            float t = s[j];
            t += __shfl_xor(t, 1);
            t += __shfl_xor(t, 2);
            t += __shfl_xor(t, 4);
            t += __shfl_xor(t, 8);
            if (lr == 0)
                atomicAdd(&rowsum[row_base + mi * 16u + kg * 4u + j], t);
        }
    }
}

__global__ void lse_log(float* __restrict__ out) {
    int i = blockIdx.x * 256 + threadIdx.x;
    if (i < MD) out[i] = logf(out[i]);
}

extern "C" void kernel_launch(void* const* d_in, const int* in_sizes, int n_in,
                              void* d_out, int out_size, void* d_ws, size_t ws_size,
                              hipStream_t stream) {
    (void)in_sizes; (void)n_in; (void)d_ws; (void)ws_size; (void)out_size;
    const float* x = (const float*)d_in[0];
    const float* W = (const float*)d_in[1];
    const float* b = (const float*)d_in[2];
    float* out = (float*)d_out;

    hipMemsetAsync(out, 0, (size_t)MD * sizeof(float), stream);

    dim3 grid((MD / BM) * (ND / BN));   // 64*32 = 2048
    dim3 block(256);
    fused_gemm_lse<<<grid, block, 0, stream>>>(x, W, b, out);
    lse_log<<<MD / 256, 256, 0, stream>>>(out);
}

// Round 2
// 376.403 us; speedup vs baseline: 1.6478x; 1.6478x over previous
//
#include <hip/hip_runtime.h>
#include <hip/hip_bf16.h>

#define MD 8192
#define KD 4096
#define ND 4096
#define BM 256
#define BN 256
#define BK 64
#define NBLK ((MD / BM) * (ND / BN))   // 32 * 16 = 512

typedef __bf16 bf16x8 __attribute__((ext_vector_type(8)));
typedef float f32x4 __attribute__((ext_vector_type(4)));

// XOR swizzle within a [row][BK] bf16 tile (row stride 128B): spreads the
// eight 16B slots of 8 consecutive rows across all 32 banks. Verified
// 0-conflict on the fragment ds_read_b128 pattern in round 1.
__device__ __forceinline__ unsigned swz(unsigned row, unsigned kbyte) {
    return row * (BK * 2u) + (kbyte ^ ((row & 7u) << 4));
}

__device__ __forceinline__ float gelu_ss(float v) {
    float t = 0.7978845608f * fmaf(0.044715f * v * v, v, v);
    float r = t * __builtin_amdgcn_rcpf(1.0f + fabsf(t));
    return 0.5f * v * (1.0f + r);
}

__global__ __launch_bounds__(512, 1) void fused_gemm_lse(
    const float* __restrict__ x, const float* __restrict__ W,
    const float* __restrict__ bias, float* __restrict__ rowsum)
{
    // [buf][A=0/B=1][256*64] bf16 = 128 KiB total
    __shared__ alignas(16) __bf16 lds[2][2][BM * BK];

    // XCD-bijective block swizzle: grid = 512, divisible by 8.
    unsigned bid  = blockIdx.x;
    unsigned sbid = (bid & 7u) * (NBLK / 8u) + (bid >> 3);
    unsigned bm = sbid / (ND / BN);
    unsigned bn = sbid % (ND / BN);

    const unsigned tid  = threadIdx.x;
    const unsigned lane = tid & 63u;
    const unsigned wid  = tid >> 6;      // 0..7
    const unsigned wr   = wid >> 2;      // wave row (0..1) -> 128 rows each
    const unsigned wc   = wid & 3u;      // wave col (0..3) -> 64 cols each
    const unsigned lr   = lane & 15u;
    const unsigned kg   = lane >> 4;

    const float* gA = x + (size_t)bm * BM * KD;
    const float* gB = W + (size_t)bn * BN * KD;

    // staging mapping: pair index f = i*512 + tid (i=0..3) over 2048 row-pairs
    // row = f>>3 (0..255), c8 = f&7 (16B bf16 slot)
    const unsigned s_row = tid >> 3;          // base row for i=0 (rows step 64 per i)
    const unsigned s_c8  = tid & 7u;

    f32x4 acc[8][4] = {};
    float4 ra[8], rb[8];   // [i*2 + half]

    auto issue = [&](const float* g, int kt, float4* r) {
        #pragma unroll
        for (int i = 0; i < 4; ++i) {
            unsigned row = s_row + 64u * i;
            size_t goff = (size_t)row * KD + (size_t)kt * BK + (size_t)s_c8 * 8u;
            r[i * 2]     = *(const float4*)(g + goff);
            r[i * 2 + 1] = *(const float4*)(g + goff + 4);
        }
    };
    auto writeT = [&](char* dst, const float4* r) {
        #pragma unroll
        for (int i = 0; i < 4; ++i) {
            unsigned row = s_row + 64u * i;
            float4 lo = r[i * 2], hi = r[i * 2 + 1];
            bf16x8 v;
            v[0]=(__bf16)lo.x; v[1]=(__bf16)lo.y; v[2]=(__bf16)lo.z; v[3]=(__bf16)lo.w;
            v[4]=(__bf16)hi.x; v[5]=(__bf16)hi.y; v[6]=(__bf16)hi.z; v[7]=(__bf16)hi.w;
            *(bf16x8*)(dst + swz(row, s_c8 * 16u)) = v;
        }
    };
    auto compute = [&](int cur) {
        const char* AsB = (const char*)&lds[cur][0][0];
        const char* BsB = (const char*)&lds[cur][1][0];
        #pragma unroll
        for (int ks = 0; ks < 2; ++ks) {
            unsigned kb = (unsigned)ks * 64u + kg * 16u;
            bf16x8 bfr[4];
            #pragma unroll
            for (int ni = 0; ni < 4; ++ni)
                bfr[ni] = *(const bf16x8*)(BsB + swz(wc * 64u + ni * 16u + lr, kb));
            #pragma unroll
            for (int mh = 0; mh < 2; ++mh) {
                bf16x8 af[4];
                #pragma unroll
                for (int a = 0; a < 4; ++a)
                    af[a] = *(const bf16x8*)(AsB + swz(wr * 128u + mh * 64u + a * 16u + lr, kb));
                __builtin_amdgcn_s_setprio(1);
                #pragma unroll
                for (int a = 0; a < 4; ++a)
                    #pragma unroll
                    for (int ni = 0; ni < 4; ++ni)
                        acc[mh * 4 + a][ni] = __builtin_amdgcn_mfma_f32_16x16x32_bf16(
                            af[a], bfr[ni], acc[mh * 4 + a][ni], 0, 0, 0);
                __builtin_amdgcn_s_setprio(0);
            }
        }
    };

    // prologue: stage tile 0
    issue(gA, 0, ra); issue(gB, 0, rb);
    writeT((char*)&lds[0][0][0], ra);
    writeT((char*)&lds[0][1][0], rb);
    __syncthreads();

    int cur = 0;
    for (int kt = 0; kt < KD / BK - 1; ++kt) {
        // T14: issue next tile's loads before compute; write after.
        issue(gA, kt + 1, ra);
        issue(gB, kt + 1, rb);
        compute(cur);
        writeT((char*)&lds[cur ^ 1][0][0], ra);
        writeT((char*)&lds[cur ^ 1][1][0], rb);
        __syncthreads();
        cur ^= 1;
    }
    compute(cur);

    // ---- epilogue: bias + leaky^2 + gelu_ss^2 + exp + per-row partial sums ----
    // C/D layout (16x16x32): col = lane&15, row = (lane>>4)*4 + j
    unsigned row_base = bm * BM + wr * 128u;
    unsigned col_base = bn * BN + wc * 64u;
    float bb[4];
    #pragma unroll
    for (int ni = 0; ni < 4; ++ni) bb[ni] = bias[col_base + ni * 16u + lr];
    #pragma unroll
    for (int mi = 0; mi < 8; ++mi) {
        float s[4] = {0.f, 0.f, 0.f, 0.f};
        #pragma unroll
        for (int ni = 0; ni < 4; ++ni) {
            #pragma unroll
            for (int j = 0; j < 4; ++j) {
                float v = acc[mi][ni][j] + bb[ni];
                v = v > 0.0f ? v : 1e-4f * v;       // two leaky-relus fused
                v = gelu_ss(gelu_ss(v));
                s[j] += __expf(v);
            }
        }
        #pragma unroll
        for (int j = 0; j < 4; ++j) {
            float t = s[j];
            t += __shfl_xor(t, 1);
            t += __shfl_xor(t, 2);
            t += __shfl_xor(t, 4);
            t += __shfl_xor(t, 8);
            if (lr == 0)
                atomicAdd(&rowsum[row_base + mi * 16u + kg * 4u + j], t);
        }
    }
}

__global__ void lse_log(float* __restrict__ out) {
    int i = blockIdx.x * 256 + threadIdx.x;
    if (i < MD) out[i] = logf(out[i]);
}

extern "C" void kernel_launch(void* const* d_in, const int* in_sizes, int n_in,
                              void* d_out, int out_size, void* d_ws, size_t ws_size,
                              hipStream_t stream) {
    (void)in_sizes; (void)n_in; (void)d_ws; (void)ws_size; (void)out_size;
    const float* x = (const float*)d_in[0];
    const float* W = (const float*)d_in[1];
    const float* b = (const float*)d_in[2];
    float* out = (float*)d_out;

    hipMemsetAsync(out, 0, (size_t)MD * sizeof(float), stream);

    dim3 grid(NBLK);    // 512, divisible by 8 -> bijective XCD swizzle
    dim3 block(512);
    fused_gemm_lse<<<grid, block, 0, stream>>>(x, W, b, out);
    lse_log<<<MD / 256, 256, 0, stream>>>(out);
}

// Round 3
// 303.256 us; speedup vs baseline: 2.0452x; 1.2412x over previous
//
#include <hip/hip_runtime.h>
#include <hip/hip_bf16.h>

#define MD 8192
#define KD 4096
#define ND 4096

typedef __bf16 bf16x8 __attribute__((ext_vector_type(8)));
typedef float f32x4 __attribute__((ext_vector_type(4)));

__device__ __forceinline__ float gelu_ss(float v) {
    float t = 0.7978845608f * fmaf(0.044715f * v * v, v, v);
    float r = t * __builtin_amdgcn_rcpf(1.0f + fabsf(t));
    return 0.5f * v * (1.0f + r);
}

// ---------------------------------------------------------------------------
// fp32 -> bf16 convert (memory-bound, vectorized 8-wide)
// ---------------------------------------------------------------------------
__global__ void cvt_bf16(const float* __restrict__ in, __bf16* __restrict__ out, int n8) {
    int i = blockIdx.x * 256 + threadIdx.x;
    int stride = gridDim.x * 256;
    for (; i < n8; i += stride) {
        const float4* p = (const float4*)(in + (size_t)i * 8);
        float4 a = p[0], b = p[1];
        bf16x8 v;
        v[0]=(__bf16)a.x; v[1]=(__bf16)a.y; v[2]=(__bf16)a.z; v[3]=(__bf16)a.w;
        v[4]=(__bf16)b.x; v[5]=(__bf16)b.y; v[6]=(__bf16)b.z; v[7]=(__bf16)b.w;
        *(bf16x8*)(out + (size_t)i * 8) = v;
    }
}

// ---------------------------------------------------------------------------
// main GEMM+epilogue: 256x256 tile, BK=32, quad-buffered LDS, global_load_lds
// staging prefetched 3 tiles ahead with counted vmcnt (T3+T4), T5 setprio.
// ---------------------------------------------------------------------------
#define BMg 256
#define BNg 256
#define BKg 32
#define KT  (KD / BKg)   // 128

__device__ __forceinline__ void gload_lds16(const void* g, void* l) {
    __builtin_amdgcn_global_load_lds(
        (const __attribute__((address_space(1))) void*)g,
        (__attribute__((address_space(3))) void*)l, 16, 0, 0);
}

__global__ __launch_bounds__(512, 2) void gemm_bf16_lse(
    const __bf16* __restrict__ xb, const __bf16* __restrict__ Wb,
    const float* __restrict__ bias, float* __restrict__ rowsum)
{
    // 4 bufs x (A,B) x 256x32 bf16 = 128 KiB
    __shared__ alignas(16) __bf16 lds[4][2][BMg * BKg];

    const unsigned nblk = (MD / BMg) * (ND / BNg);   // 32*16 = 512
    unsigned bid  = blockIdx.x;
    unsigned sbid = (bid & 7u) * (nblk / 8u) + (bid >> 3);
    unsigned bm = sbid / (ND / BNg);
    unsigned bn = sbid % (ND / BNg);

    const unsigned tid  = threadIdx.x;
    const unsigned lane = tid & 63u;
    const unsigned wid  = tid >> 6;      // 0..7
    const unsigned wr   = wid >> 2;      // 0..1 -> 128 rows
    const unsigned wc   = wid & 3u;      // 0..3 -> 64 cols
    const unsigned lr   = lane & 15u;
    const unsigned kg   = lane >> 4;

    // --- staging source addresses (per-lane, pre-swizzled: c ^= (row>>1)&3) ---
    // slot s = tid + i*512 ; row = s>>2 ; c = s&3 (16B col-slot of 64B row)
    unsigned s0 = tid, s1 = tid + 512u;
    unsigned r0 = s0 >> 2, c0 = s0 & 3u;
    unsigned r1 = s1 >> 2, c1 = s1 & 3u;
    unsigned cg0 = c0 ^ ((r0 >> 1) & 3u);
    unsigned cg1 = c1 ^ ((r1 >> 1) & 3u);
    const __bf16* ga0 = xb + (size_t)(bm * BMg + r0) * KD + cg0 * 8u;
    const __bf16* ga1 = xb + (size_t)(bm * BMg + r1) * KD + cg1 * 8u;
    const __bf16* gb0 = Wb + (size_t)(bn * BNg + r0) * KD + cg0 * 8u;
    const __bf16* gb1 = Wb + (size_t)(bn * BNg + r1) * KD + cg1 * 8u;

    f32x4 acc[8][4] = {};

    // stage one K-tile (A+B = 4 global_load_lds/thread); advances pointers.
    auto stage = [&](unsigned bsel) {
        gload_lds16(ga0, &lds[bsel][0][(wid * 64u + 0u * 512u) * 8u]);
        gload_lds16(ga1, &lds[bsel][0][(wid * 64u + 1u * 512u) * 8u]);
        gload_lds16(gb0, &lds[bsel][1][(wid * 64u + 0u * 512u) * 8u]);
        gload_lds16(gb1, &lds[bsel][1][(wid * 64u + 1u * 512u) * 8u]);
        ga0 += BKg; ga1 += BKg; gb0 += BKg; gb1 += BKg;
    };

    auto compute = [&](unsigned bsel) {
        const char* AsB = (const char*)&lds[bsel][0][0];
        const char* BsB = (const char*)&lds[bsel][1][0];
        bf16x8 bfr[4], afr[8];
        #pragma unroll
        for (int nf = 0; nf < 4; ++nf) {
            unsigned row = wc * 64u + nf * 16u + lr;
            bfr[nf] = *(const bf16x8*)(BsB + row * 64u + (kg ^ ((row >> 1) & 3u)) * 16u);
        }
        #pragma unroll
        for (int mf = 0; mf < 8; ++mf) {
            unsigned row = wr * 128u + mf * 16u + lr;
            afr[mf] = *(const bf16x8*)(AsB + row * 64u + (kg ^ ((row >> 1) & 3u)) * 16u);
        }
        __builtin_amdgcn_s_setprio(1);
        #pragma unroll
        for (int mf = 0; mf < 8; ++mf)
            #pragma unroll
            for (int nf = 0; nf < 4; ++nf)
                acc[mf][nf] = __builtin_amdgcn_mfma_f32_16x16x32_bf16(
                    afr[mf], bfr[nf], acc[mf][nf], 0, 0, 0);
        __builtin_amdgcn_s_setprio(0);
    };

    // prologue: prefetch tiles 0,1,2
    stage(0); stage(1); stage(2);

    for (int t = 0; t < KT - 3; ++t) {            // t = 0..124
        asm volatile("s_waitcnt vmcnt(8)" ::: "memory");  // tile t landed (FIFO)
        __builtin_amdgcn_s_barrier();
        __builtin_amdgcn_sched_barrier(0);
        stage((unsigned)(t + 3) & 3u);            // buf[(t-1)&3]: safe post-barrier
        compute((unsigned)t & 3u);
    }
    asm volatile("s_waitcnt vmcnt(8)" ::: "memory");
    __builtin_amdgcn_s_barrier();
    __builtin_amdgcn_sched_barrier(0);
    compute((KT - 3) & 3u);                       // t=125
    asm volatile("s_waitcnt vmcnt(4)" ::: "memory");
    __builtin_amdgcn_s_barrier();
    __builtin_amdgcn_sched_barrier(0);
    compute((KT - 2) & 3u);                       // t=126
    asm volatile("s_waitcnt vmcnt(0)" ::: "memory");
    __builtin_amdgcn_s_barrier();
    __builtin_amdgcn_sched_barrier(0);
    compute((KT - 1) & 3u);                       // t=127

    // ---- epilogue: bias + leaky^2 + gelu^2 + exp + row partial sums ----
    // C/D layout: col = lane&15 (=lr), row = kg*4 + j
    unsigned row_base = bm * BMg + wr * 128u;
    unsigned col_base = bn * BNg + wc * 64u;
    float bb[4];
    #pragma unroll
    for (int nf = 0; nf < 4; ++nf) bb[nf] = bias[col_base + nf * 16u + lr];
    #pragma unroll
    for (int mf = 0; mf < 8; ++mf) {
        float s[4] = {0.f, 0.f, 0.f, 0.f};
        #pragma unroll
        for (int nf = 0; nf < 4; ++nf) {
            #pragma unroll
            for (int j = 0; j < 4; ++j) {
                float v = acc[mf][nf][j] + bb[nf];
                v = v > 0.0f ? v : 1e-4f * v;      // two leaky-relus fused
                v = gelu_ss(gelu_ss(v));
                s[j] += __expf(v);
            }
        }
        #pragma unroll
        for (int j = 0; j < 4; ++j) {
            float t = s[j];
            t += __shfl_xor(t, 1);
            t += __shfl_xor(t, 2);
            t += __shfl_xor(t, 4);
            t += __shfl_xor(t, 8);
            if (lr == 0)
                atomicAdd(&rowsum[row_base + mf * 16u + kg * 4u + j], t);
        }
    }
}

// ---------------------------------------------------------------------------
// Fallback (round-2 kernel): fused fp32 staging, used if ws too small.
// ---------------------------------------------------------------------------
#define BM 256
#define BN 256
#define BK 64
#define NBLK ((MD / BM) * (ND / BN))

__device__ __forceinline__ unsigned swz(unsigned row, unsigned kbyte) {
    return row * (BK * 2u) + (kbyte ^ ((row & 7u) << 4));
}

__global__ __launch_bounds__(512, 1) void fused_gemm_lse(
    const float* __restrict__ x, const float* __restrict__ W,
    const float* __restrict__ bias, float* __restrict__ rowsum)
{
    __shared__ alignas(16) __bf16 lds[2][2][BM * BK];
    unsigned bid  = blockIdx.x;
    unsigned sbid = (bid & 7u) * (NBLK / 8u) + (bid >> 3);
    unsigned bm = sbid / (ND / BN);
    unsigned bn = sbid % (ND / BN);
    const unsigned tid  = threadIdx.x;
    const unsigned lane = tid & 63u;
    const unsigned wid  = tid >> 6;
    const unsigned wr   = wid >> 2;
    const unsigned wc   = wid & 3u;
    const unsigned lr   = lane & 15u;
    const unsigned kg   = lane >> 4;
    const float* gA = x + (size_t)bm * BM * KD;
    const float* gB = W + (size_t)bn * BN * KD;
    const unsigned s_row = tid >> 3;
    const unsigned s_c8  = tid & 7u;
    f32x4 acc[8][4] = {};
    float4 ra[8], rb[8];
    auto issue = [&](const float* g, int kt, float4* r) {
        #pragma unroll
        for (int i = 0; i < 4; ++i) {
            unsigned row = s_row + 64u * i;
            size_t goff = (size_t)row * KD + (size_t)kt * BK + (size_t)s_c8 * 8u;
            r[i * 2]     = *(const float4*)(g + goff);
            r[i * 2 + 1] = *(const float4*)(g + goff + 4);
        }
    };
    auto writeT = [&](char* dst, const float4* r) {
        #pragma unroll
        for (int i = 0; i < 4; ++i) {
            unsigned row = s_row + 64u * i;
            float4 lo = r[i * 2], hi = r[i * 2 + 1];
            bf16x8 v;
            v[0]=(__bf16)lo.x; v[1]=(__bf16)lo.y; v[2]=(__bf16)lo.z; v[3]=(__bf16)lo.w;
            v[4]=(__bf16)hi.x; v[5]=(__bf16)hi.y; v[6]=(__bf16)hi.z; v[7]=(__bf16)hi.w;
            *(bf16x8*)(dst + swz(row, s_c8 * 16u)) = v;
        }
    };
    auto compute = [&](int cur) {
        const char* AsB = (const char*)&lds[cur][0][0];
        const char* BsB = (const char*)&lds[cur][1][0];
        #pragma unroll
        for (int ks = 0; ks < 2; ++ks) {
            unsigned kb = (unsigned)ks * 64u + kg * 16u;
            bf16x8 bfr[4];
            #pragma unroll
            for (int ni = 0; ni < 4; ++ni)
                bfr[ni] = *(const bf16x8*)(BsB + swz(wc * 64u + ni * 16u + lr, kb));
            #pragma unroll
            for (int mh = 0; mh < 2; ++mh) {
                bf16x8 af[4];
                #pragma unroll
                for (int a = 0; a < 4; ++a)
                    af[a] = *(const bf16x8*)(AsB + swz(wr * 128u + mh * 64u + a * 16u + lr, kb));
                __builtin_amdgcn_s_setprio(1);
                #pragma unroll
                for (int a = 0; a < 4; ++a)
                    #pragma unroll
                    for (int ni = 0; ni < 4; ++ni)
                        acc[mh * 4 + a][ni] = __builtin_amdgcn_mfma_f32_16x16x32_bf16(
                            af[a], bfr[ni], acc[mh * 4 + a][ni], 0, 0, 0);
                __builtin_amdgcn_s_setprio(0);
            }
        }
    };
    issue(gA, 0, ra); issue(gB, 0, rb);
    writeT((char*)&lds[0][0][0], ra);
    writeT((char*)&lds[0][1][0], rb);
    __syncthreads();
    int cur = 0;
    for (int kt = 0; kt < KD / BK - 1; ++kt) {
        issue(gA, kt + 1, ra);
        issue(gB, kt + 1, rb);
        compute(cur);
        writeT((char*)&lds[cur ^ 1][0][0], ra);
        writeT((char*)&lds[cur ^ 1][1][0], rb);
        __syncthreads();
        cur ^= 1;
    }
    compute(cur);
    unsigned row_base = bm * BM + wr * 128u;
    unsigned col_base = bn * BN + wc * 64u;
    float bb[4];
    #pragma unroll
    for (int ni = 0; ni < 4; ++ni) bb[ni] = bias[col_base + ni * 16u + lr];
    #pragma unroll
    for (int mi = 0; mi < 8; ++mi) {
        float s[4] = {0.f, 0.f, 0.f, 0.f};
        #pragma unroll
        for (int ni = 0; ni < 4; ++ni) {
            #pragma unroll
            for (int j = 0; j < 4; ++j) {
                float v = acc[mi][ni][j] + bb[ni];
                v = v > 0.0f ? v : 1e-4f * v;
                v = gelu_ss(gelu_ss(v));
                s[j] += __expf(v);
            }
        }
        #pragma unroll
        for (int j = 0; j < 4; ++j) {
            float t = s[j];
            t += __shfl_xor(t, 1);
            t += __shfl_xor(t, 2);
            t += __shfl_xor(t, 4);
            t += __shfl_xor(t, 8);
            if (lr == 0)
                atomicAdd(&rowsum[row_base + mi * 16u + kg * 4u + j], t);
        }
    }
}

__global__ void lse_log(float* __restrict__ out) {
    int i = blockIdx.x * 256 + threadIdx.x;
    if (i < MD) out[i] = logf(out[i]);
}

extern "C" void kernel_launch(void* const* d_in, const int* in_sizes, int n_in,
                              void* d_out, int out_size, void* d_ws, size_t ws_size,
                              hipStream_t stream) {
    (void)in_sizes; (void)n_in; (void)out_size;
    const float* x = (const float*)d_in[0];
    const float* W = (const float*)d_in[1];
    const float* b = (const float*)d_in[2];
    float* out = (float*)d_out;

    hipMemsetAsync(out, 0, (size_t)MD * sizeof(float), stream);

    size_t need = ((size_t)MD * KD + (size_t)ND * KD) * sizeof(__bf16);  // 100.7 MB
    if (ws_size >= need) {
        __bf16* xb = (__bf16*)d_ws;
        __bf16* Wb = xb + (size_t)MD * KD;
        cvt_bf16<<<2048, 256, 0, stream>>>(x, xb, MD * KD / 8);
        cvt_bf16<<<2048, 256, 0, stream>>>(W, Wb, ND * KD / 8);
        gemm_bf16_lse<<<(MD / BMg) * (ND / BNg), 512, 0, stream>>>(xb, Wb, b, out);
    } else {
        fused_gemm_lse<<<NBLK, 512, 0, stream>>>(x, W, b, out);
    }
    lse_log<<<MD / 256, 256, 0, stream>>>(out);
}